// Round 9
// baseline (463.163 us; speedup 1.0000x reference)
//
#include <hip/hip_runtime.h>
#include <cstdint>
#include <cstddef>

// Problem constants (fixed by reference file)
#define NB_N 100000
#define E_N  131072
#define T_N  16384
#define D_N  512
#define NCLS 40
#define NT64 1563           // ceil(100000/64); 1563*64 = 100032
#define CAPR 12             // legacy-path register z-cache edges/target

typedef unsigned short u16;
typedef unsigned int   u32;
typedef __attribute__((ext_vector_type(8))) short  short8;   // 8 bf16 (4 VGPRs)
typedef __attribute__((ext_vector_type(4))) float  floatx4;  // MFMA accumulator

// ---------- bf16 helpers (manual, RNE) ----------
__device__ __forceinline__ u16 f2bf(float f) {
  u32 u = __float_as_uint(f);
  return (u16)((u + 0x7fffu + ((u >> 16) & 1u)) >> 16);
}
__device__ __forceinline__ void unpack8(uint4 z, float* f) {
  f[0] = __uint_as_float(z.x << 16);
  f[1] = __uint_as_float(z.x & 0xffff0000u);
  f[2] = __uint_as_float(z.y << 16);
  f[3] = __uint_as_float(z.y & 0xffff0000u);
  f[4] = __uint_as_float(z.z << 16);
  f[5] = __uint_as_float(z.z & 0xffff0000u);
  f[6] = __uint_as_float(z.w << 16);
  f[7] = __uint_as_float(z.w & 0xffff0000u);
}
__device__ __forceinline__ void gload_lds16(const void* g, void* s) {
  __builtin_amdgcn_global_load_lds(
      (const __attribute__((address_space(1))) unsigned int*)g,
      (__attribute__((address_space(3))) unsigned int*)s, 16, 0, 0);
}
// packed f32x2 -> bf16x2 (RNE), hw instruction; bit-identical to f2bf on finite vals
__device__ __forceinline__ u32 cvtpk_bf16(float lo, float hi) {
  u32 r;
  asm("v_cvt_pk_bf16_f32 %0, %1, %2" : "=v"(r) : "v"(lo), "v"(hi));
  return r;
}

// ---------- kernel 0: transpose+convert pca_w (K,N) f32 -> Bt (N,K) bf16 ----------
__global__ void conv_bt(const float* __restrict__ w, u16* __restrict__ Bt) {
  int i = blockIdx.x * 256 + threadIdx.x;       // i over 512*512, i = n*512+k
  int n = i >> 9, k = i & 511;
  Bt[i] = f2bf(w[k * 512 + n]);
}

// ---------- kernel 0b: transpose+convert mlp_w (512,40) f32 -> Bt2 (64,512) bf16, zero-pad ----
__global__ void conv_bt2(const float* __restrict__ w, u16* __restrict__ Bt2) {
  int i = blockIdx.x * 256 + threadIdx.x;       // 64*512 elements, i = n*512+k
  int n = i >> 9, k = i & 511;
  Bt2[i] = (n < NCLS) ? f2bf(w[k * NCLS + n]) : (u16)0;
}

// ---------- kernel 1: CSR offsets from sorted row_idx ----------
__global__ void build_offs(const int* __restrict__ rowi, int* __restrict__ offs) {
  int e = blockIdx.x * 256 + threadIdx.x;
  if (e >= E_N) return;
  int r  = rowi[e];
  int rp = (e == 0) ? -1 : rowi[e - 1];
  for (int t = rp + 1; t <= r; ++t) offs[t] = e;
  if (e == E_N - 1)
    for (int t = r + 1; t <= T_N; ++t) offs[t] = E_N;
}

// ---------- kernel 2: segment softmax of ppr ----------
__global__ void ppr_sm(const float* __restrict__ ppr, const int* __restrict__ offs,
                       float* __restrict__ pprn) {
  int t = blockIdx.x * 256 + threadIdx.x;       // T_N threads
  int s = offs[t], en = offs[t + 1];
  if (s >= en) return;
  float m = -INFINITY;
  for (int e = s; e < en; ++e) m = fmaxf(m, ppr[e]);
  float sum = 0.f;
  for (int e = s; e < en; ++e) sum += expf(ppr[e] - m);
  float inv = 1.f / sum;
  for (int e = s; e < en; ++e) pprn[e] = expf(ppr[e] - m) * inv;
}

// ---------- kernel 3: bf16 MFMA GEMM x = relu(x_nb @ pca_w + b), per-capsule l2norm,
//            writes xn bf16.
//            R13: 64x128 tile, 256 thr (4 waves 2m x 2n, 32-row m-waves), BK=64,
//            FOUR blocks/CU. Blocks/CU trend: 1->183us, 2->150, 3->130 (R6/R3/R7);
//            this continues the only lever with a verified causal win.
//            acc[2][4] (32 AGPR) + 16 staging regs -> ~105 total, fits the
//            (256,4) 128-reg cap without spill; LDS = As 8KB + Bs dbuf 32KB
//            = 40KB -> 4 blocks/CU = 16 waves. Counted-vmcnt 2-barrier schedule
//            carried over verbatim (issueA = 4 loads; steady in-flight
//            B(s+2)+A(s+2) = 8 -> vmcnt(8); writeA's implicit reg-wait
//            transitively drains B(s+1)). ----------
__global__ __launch_bounds__(256, 4) void gemm_pca(
    const float* __restrict__ A,    // x_nb (NB,512) f32
    const u16*   __restrict__ Bt,   // (512,512) bf16, n-major (pre-transposed)
    const float* __restrict__ bias, // (512,)
    u16*         __restrict__ xn) { // (NB,512) bf16, normalized
  __shared__ u16 SMEM[20480];       // 40 KB: As 64x64 (8KB) | Bs dbuf 2x 128x64 (32KB)
  u16* As = SMEM;
  u16* Bs = SMEM + 4096;            // buffer b at Bs + b*8192
  const int tid  = threadIdx.x;
  const int wid  = tid >> 6, lane = tid & 63;
  const int quad = lane >> 4, l16 = lane & 15;
  // XCD-grouped decode: b = 32g + 8n + mlow -> mt = 8g+mlow, n in {0..3}.
  // Same-mt blocks differ by 8 in flat id -> same XCD -> shared A-tile in L2.
  const int b  = blockIdx.x;
  const int mt = (b & 7) | ((b >> 5) << 3);
  if (mt >= NT64) return;
  const int m0 = mt * 64;
  const int n0 = ((b >> 3) & 3) * 128;
  const int wm = (wid >> 1) * 32;   // 2 m-waves of 32 rows
  const int wn = (wid & 1) * 64;    // 2 n-waves of 64 cols
  const int sw = l16 & 7;           // per-lane chunk swizzle for frag reads

  floatx4 acc[2][4];
#pragma unroll
  for (int i = 0; i < 2; ++i)
#pragma unroll
    for (int j = 0; j < 4; ++j) acc[i][j] = (floatx4){0.f, 0.f, 0.f, 0.f};

  float4 pa0[2], pa1[2];            // in-flight A regs: 2 units x 2 float4 (4 loads)

  // 4 unconditional global loads for the 64x64 f32 A-tile of one k-step
  // (clamped rows: tail re-reads row NB_N-1, never stored) -> exact vmcnt.
  auto issueA = [&](int k0) {
#pragma unroll
    for (int j = 0; j < 2; ++j) {
      int ci = j * 256 + tid;                 // 512 units (8 f32 each): row=ci>>3, kc=ci&7
      int row = ci >> 3, kc = ci & 7;
      int gm = m0 + row;
      if (gm > NB_N - 1) gm = NB_N - 1;
      const float* src = A + (size_t)gm * 512 + k0 + kc * 8;
      pa0[j] = *(const float4*)(src);
      pa1[j] = *(const float4*)(src + 4);
    }
  };
  // cvt + dest-swizzled ds_write of in-flight A regs (compiler emits the vmcnt)
  auto writeA = [&]() {
#pragma unroll
    for (int j = 0; j < 2; ++j) {
      int ci = j * 256 + tid;
      int row = ci >> 3, kc = ci & 7;
      uint4 pk;
      pk.x = cvtpk_bf16(pa0[j].x, pa0[j].y);
      pk.y = cvtpk_bf16(pa0[j].z, pa0[j].w);
      pk.z = cvtpk_bf16(pa1[j].x, pa1[j].y);
      pk.w = cvtpk_bf16(pa1[j].z, pa1[j].w);
      int dc = kc ^ (row & 7);                // dest-side swizzle
      *(uint4*)(&As[(size_t)(row * 8 + dc) * 8]) = pk;
    }
  };
  // 4 DMA chunks of B-tile (128 rows x 64 k), source-side swizzle, dest contiguous
  auto issueB = [&](int k0, u16* dstB) {
#pragma unroll
    for (int j = 0; j < 4; ++j) {
      int ci  = j * 256 + wid * 64 + lane;    // 1024 chunks
      int row = ci >> 3;
      int kcs = (lane & 7) ^ ((lane >> 3) & 7);
      gload_lds16(Bt + (size_t)(n0 + row) * 512 + k0 + kcs * 8,
                  &dstB[(size_t)(j * 256 + wid * 64) * 8]);
    }
  };

  // ---- prologue: A0, B0, B1 staged; A1 in flight ----
  issueA(0);                          // A0: 4 loads
  issueB(0, Bs);                      // B0 -> slot 0 (4 DMA)
  issueB(64, Bs + 8192);              // B1 -> slot 1 (4 DMA)
  writeA();                           // implicit vmcnt(8): A0 done; B0,B1 in flight
  issueA(64);                         // A1: 4 loads
  asm volatile("s_waitcnt vmcnt(8) lgkmcnt(0)" ::: "memory");  // drain B0; keep B1+A1
  __builtin_amdgcn_s_barrier();
  __builtin_amdgcn_sched_barrier(0);

  // ---- main loop: 8 k-steps, 2 barriers/step; B issued 2 steps ahead ----
#pragma unroll
  for (int s = 0; s < 8; ++s) {
    const int cs = s & 1;
    const u16* Bsc = Bs + cs * 8192;
    // compute step s (reads As + Bsc)
#pragma unroll
    for (int kk = 0; kk < 64; kk += 32) {
      short8 af[2], bf[4];
#pragma unroll
      for (int mi = 0; mi < 2; ++mi) {
        int c = (kk >> 3) + quad;
        af[mi] = *(const short8*)(&As[(wm + mi * 16 + l16) * 64 + ((c ^ sw) << 3)]);
      }
#pragma unroll
      for (int ni = 0; ni < 4; ++ni) {
        int c = (kk >> 3) + quad;
        bf[ni] = *(const short8*)(&Bsc[(wn + ni * 16 + l16) * 64 + ((c ^ sw) << 3)]);
      }
#pragma unroll
      for (int mi = 0; mi < 2; ++mi)
#pragma unroll
        for (int ni = 0; ni < 4; ++ni)
          acc[mi][ni] = __builtin_amdgcn_mfma_f32_16x16x32_bf16(af[mi], bf[ni],
                                                                acc[mi][ni], 0, 0, 0);
    }
    // barrier 1: all waves done READING As + Bs[cs] (slot cs now free)
    __builtin_amdgcn_s_barrier();
    __builtin_amdgcn_sched_barrier(0);
    if (s + 1 < 8) {
      if (s + 2 < 8) issueB((s + 2) * 64, Bs + cs * 8192);  // slot (s+2)&1 == cs
      writeA();                       // implicit wait: A(s+1) done -> B(s+1) (older) done
      if (s + 2 < 8) {
        issueA((s + 2) * 64);         // refill A regs (4 loads)
        asm volatile("s_waitcnt vmcnt(8) lgkmcnt(0)" ::: "memory");  // keep B(s+2)+A(s+2)
      } else {
        asm volatile("s_waitcnt vmcnt(0) lgkmcnt(0)" ::: "memory");   // tail: drain all
      }
      __builtin_amdgcn_s_barrier();   // barrier 2: As written + B(s+1) resident
      __builtin_amdgcn_sched_barrier(0);
    }
  }
  __syncthreads();                    // all compute done before Os overwrites SMEM

  // epilogue: +bias, relu, per-capsule (64-col) l2norm -> LDS tile -> full-line stores
  u16* Os = SMEM;                     // 64x128 u16 = 16 KB (As/Bs dead)
#pragma unroll
  for (int mi = 0; mi < 2; ++mi) {
#pragma unroll
    for (int r = 0; r < 4; ++r) {
      int lrow = wm + mi * 16 + quad * 4 + r;
      float v[4];
      float ss = 0.f;
#pragma unroll
      for (int ni = 0; ni < 4; ++ni) {
        int n  = n0 + wn + ni * 16 + l16;
        float x = acc[mi][ni][r] + bias[n];
        x = fmaxf(x, 0.f);
        v[ni] = x;
        ss += x * x;
      }
      ss += __shfl_xor(ss, 1);
      ss += __shfl_xor(ss, 2);
      ss += __shfl_xor(ss, 4);
      ss += __shfl_xor(ss, 8);
      float sc = 1.f / fmaxf(sqrtf(ss), 1e-12f);
#pragma unroll
      for (int ni = 0; ni < 4; ++ni)
        Os[lrow * 128 + wn + ni * 16 + l16] = f2bf(v[ni] * sc);
    }
  }
  __syncthreads();
#pragma unroll
  for (int c8 = 0; c8 < 4; ++c8) {    // 1024 16B-chunks, 4 per thread
    int idx = c8 * 256 + tid;
    int row = idx >> 4, chk = idx & 15;
    int gm = m0 + row;
    if (gm < NB_N) {
      uint4 val = *(const uint4*)(&Os[row * 128 + chk * 8]);
      *(uint4*)(xn + (size_t)gm * 512 + n0 + chk * 8) = val;
    }
  }
}

// ---------- fast-path helpers for kernel 4 ----------
// matvec in coefficient space: e_i = sum_j G[i][j] * w[j], rows i0 / i0+8 per lane.
// w[c][j] lives at lane (c*8 | (j&7)), register w0 (j<8) / w1 (j>=8).
__device__ __forceinline__ void matvec16(const float (&g0)[16], const float (&g1)[16],
                                         float w0, float w1, int base,
                                         float& e0, float& e1) {
  e0 = 0.f; e1 = 0.f;
#pragma unroll
  for (int j = 0; j < 8; ++j) {
    float wj = __shfl(w0, base | j);
    e0 += g0[j] * wj;
    e1 += g1[j] * wj;
  }
#pragma unroll
  for (int j = 0; j < 8; ++j) {
    float wj = __shfl(w1, base | j);
    e0 += g0[8 + j] * wj;
    e1 += g1[8 + j] * wj;
  }
}

// segment softmax over edges of one capsule: values d0 (edge i0), d1 (edge i0+8),
// reduction across the 8 lanes of the capsule group (xor 1,2,4). Invalid -> 0.
__device__ __forceinline__ void segsm2(float& d0, float& d1, bool v0, bool v1) {
  float m = fmaxf(v0 ? d0 : -INFINITY, v1 ? d1 : -INFINITY);
  m = fmaxf(m, __shfl_xor(m, 1));
  m = fmaxf(m, __shfl_xor(m, 2));
  m = fmaxf(m, __shfl_xor(m, 4));
  float e0 = v0 ? expf(d0 - m) : 0.f;
  float e1 = v1 ? expf(d1 - m) : 0.f;
  float s = e0 + e1;
  s += __shfl_xor(s, 1);
  s += __shfl_xor(s, 2);
  s += __shfl_xor(s, 4);
  float inv = 1.f / s;
  d0 = e0 * inv;
  d1 = e1 * inv;
}

// ---------- kernel 4: ALL routing (init + 3 rounds), one target per wave.
//            FAST PATH (deg<=16, ~99.6% of targets): per-capsule Gram matrices
//            G_c = Z_c Z_c^T via 2 MFMAs/capsule; all 3 routing rounds run in
//            deg-dim coefficient space. LEGACY PATH (deg>16): edge loop. ----------
__global__ __launch_bounds__(128, 4) void fused_all(
    const u16* __restrict__ xn, const int* __restrict__ coli,
    const int* __restrict__ offs, const float* __restrict__ pprn,
    u16* __restrict__ ub) {
  // per-wave Gram staging: stored[c][a][b] = G_c[b][a], 260-float capsule stride
  __shared__ __align__(16) float Glds[2][8 * 260];
  const int lane = threadIdx.x & 63;
  const int wv = threadIdx.x >> 6;
  const int t = blockIdx.x * 2 + wv;
  const int s = offs[t], en = offs[t + 1];
  int deg = en - s;
  if (deg > 64) deg = 64;           // Poisson(8): max over 16k targets ~27

  int   mycol = (lane < deg) ? coli[s + lane] : 0;
  float myppr = (lane < deg) ? pprn[s + lane] : 0.f;

  float uf[8] = {0.f, 0.f, 0.f, 0.f, 0.f, 0.f, 0.f, 0.f};

  if (deg <= 16) {
    // ================= fast path =================
    float* G = Glds[wv];
    // 1) gather z fragments (lane: edge=lane&15, k-chunk=lane>>4) and build Grams
    const int esrc = lane & 15, kq = lane >> 4;
    int ce = __shfl(mycol, esrc);                 // edges >= deg read row 0 (masked later)
    const u16* zb = xn + (size_t)ce * 512 + kq * 8;
    floatx4 gram[8];
#pragma unroll
    for (int c = 0; c < 8; ++c) {
      short8 f0 = *(const short8*)(zb + c * 64);
      short8 f1 = *(const short8*)(zb + c * 64 + 32);
      floatx4 gg = (floatx4){0.f, 0.f, 0.f, 0.f};
      gg = __builtin_amdgcn_mfma_f32_16x16x32_bf16(f0, f0, gg, 0, 0, 0);
      gg = __builtin_amdgcn_mfma_f32_16x16x32_bf16(f1, f1, gg, 0, 0, 0);
      gram[c] = gg;
    }
    // 2) D layout: lane holds G[i=kq*4+r][j=esrc]; store as [c][esrc][kq*4+r]
#pragma unroll
    for (int c = 0; c < 8; ++c)
      *(float4*)&G[c * 260 + esrc * 16 + kq * 4] = *(float4*)&gram[c];
    // 3) lane (c=lane>>3, i0=lane&7) loads rows i0 and i0+8 of its capsule's Gram
    const int cc = lane >> 3, i0 = lane & 7;
    const int base = lane & 56;                   // == cc*8, bpermute broadcast base
    float g0[16], g1[16];
    {
      const float* r0 = &G[cc * 260 + i0 * 16];
      const float* r1 = &G[cc * 260 + (i0 + 8) * 16];
#pragma unroll
      for (int ch = 0; ch < 4; ++ch) {
        float4 a = *(const float4*)(r0 + ch * 4);
        float4 b = *(const float4*)(r1 + ch * 4);
        g0[ch * 4 + 0] = a.x; g0[ch * 4 + 1] = a.y;
        g0[ch * 4 + 2] = a.z; g0[ch * 4 + 3] = a.w;
        g1[ch * 4 + 0] = b.x; g1[ch * 4 + 1] = b.y;
        g1[ch * 4 + 2] = b.z; g1[ch * 4 + 3] = b.w;
      }
    }
    const bool v0 = i0 < deg, v1 = (i0 + 8) < deg;
    float pr0 = __shfl(myppr, i0);                // ppr[i0], 0 if invalid
    float pr1 = __shfl(myppr, i0 + 8);

    // init logits: d = G . ppr  (== <u0, z_i>, u0 = sum ppr_j z_j, unnormalized)
    float d0, d1;
    matvec16(g0, g1, pr0, pr1, base, d0, d1);

    float w0 = 0.f, w1 = 0.f;
#pragma unroll
    for (int it = 0; it < 3; ++it) {
      segsm2(d0, d1, v0, v1);                     // first segment softmax
      d0 = 0.5f * d0 + 0.5f * pr0;                // blend with pprn (invalid: 0+0)
      d1 = 0.5f * d1 + 0.5f * pr1;
      segsm2(d0, d1, v0, v1);                     // second segment softmax -> P
      w0 = d0; w1 = d1;                           // coefficients (invalid == 0)
      if (it < 2) {
        // e = G.P serves both the l2norm (||u||^2 = P^T G P) and next logits
        float e0, e1;
        matvec16(g0, g1, w0, w1, base, e0, e1);
        float nv = w0 * e0 + w1 * e1;
        nv += __shfl_xor(nv, 1);
        nv += __shfl_xor(nv, 2);
        nv += __shfl_xor(nv, 4);
        float invn = 1.f / fmaxf(sqrtf(nv), 1e-12f);
        d0 = e0 * invn;
        d1 = e1 * invn;
      }
    }

    // final reconstruction: u = sum_j P2_j z_j (lane holds dims of capsule lane>>3)
#pragma unroll
    for (int j = 0; j < 16; ++j) {
      if (j < deg) {                              // wave-uniform branch
        float wj = __shfl((j < 8) ? w0 : w1, base | (j & 7));
        int cj = __shfl(mycol, j);
        uint4 zz = *(const uint4*)(xn + (size_t)cj * 512 + lane * 8);
        float zf[8];
        unpack8(zz, zf);
#pragma unroll
        for (int q = 0; q < 8; ++q) uf[q] += wj * zf[q];
      }
    }
  } else {
    // ================= legacy path (deg > 16, ~0.4% of targets) =================
    const int cap = lane >> 3;
    const int slot = lane >> 3;

    uint4 zreg[CAPR];
#pragma unroll
    for (int j = 0; j < CAPR; ++j) {
      if (j < deg) {
        int c = __shfl(mycol, j);
        zreg[j] = *(const uint4*)(xn + (size_t)c * 512 + lane * 8);
      }
    }

    // init: u0 = sum_e pprn_e * z_e
#pragma unroll
    for (int j = 0; j < CAPR; ++j) {
      if (j < deg) {
        float w = __shfl(myppr, j);
        float zf[8];
        unpack8(zreg[j], zf);
#pragma unroll
        for (int q = 0; q < 8; ++q) uf[q] += w * zf[q];
      }
    }
    for (int j = CAPR; j < deg; ++j) {
      float w = __shfl(myppr, j);
      int c = __shfl(mycol, j);
      uint4 zz = *(const uint4*)(xn + (size_t)c * 512 + lane * 8);
      float zf[8];
      unpack8(zz, zf);
#pragma unroll
      for (int q = 0; q < 8; ++q) uf[q] += w * zf[q];
    }

    float Preg[8];

    for (int it = 0; it < 3; ++it) {
      // ---- phase 1: capsule logits ----
#pragma unroll
      for (int j = 0; j < CAPR; ++j) {
        if (j < deg) {
          float zf[8];
          unpack8(zreg[j], zf);
          float d = uf[0]*zf[0] + uf[1]*zf[1] + uf[2]*zf[2] + uf[3]*zf[3] +
                    uf[4]*zf[4] + uf[5]*zf[5] + uf[6]*zf[6] + uf[7]*zf[7];
          d += __shfl_xor(d, 1);
          d += __shfl_xor(d, 2);
          d += __shfl_xor(d, 4);
          float dc = __shfl(d, (lane & 7) << 3);
          if (slot == (j & 7)) Preg[j >> 3] = dc;
        }
      }
      for (int j = CAPR; j < deg; ++j) {
        int c = __shfl(mycol, j);
        uint4 zz = *(const uint4*)(xn + (size_t)c * 512 + lane * 8);
        float zf[8];
        unpack8(zz, zf);
        float d = uf[0]*zf[0] + uf[1]*zf[1] + uf[2]*zf[2] + uf[3]*zf[3] +
                  uf[4]*zf[4] + uf[5]*zf[5] + uf[6]*zf[6] + uf[7]*zf[7];
        d += __shfl_xor(d, 1);
        d += __shfl_xor(d, 2);
        d += __shfl_xor(d, 4);
        float dc = __shfl(d, (lane & 7) << 3);
        if (slot == (j & 7)) {
          int hi = j >> 3;
          if      (hi == 1) Preg[1] = dc;
          else if (hi == 2) Preg[2] = dc;
          else if (hi == 3) Preg[3] = dc;
          else if (hi == 4) Preg[4] = dc;
          else if (hi == 5) Preg[5] = dc;
          else if (hi == 6) Preg[6] = dc;
          else if (hi == 7) Preg[7] = dc;
        }
      }

      // ---- phase 2: segsm -> blend -> segsm ----
      {
        float m1 = -INFINITY;
#pragma unroll
        for (int i = 0; i < 8; ++i)
          m1 = (slot + 8*i < deg) ? fmaxf(m1, Preg[i]) : m1;
        m1 = fmaxf(m1, __shfl_xor(m1, 8));
        m1 = fmaxf(m1, __shfl_xor(m1, 16));
        m1 = fmaxf(m1, __shfl_xor(m1, 32));
        float s1 = 0.f;
#pragma unroll
        for (int i = 0; i < 8; ++i)
          s1 += (slot + 8*i < deg) ? expf(Preg[i] - m1) : 0.f;
        s1 += __shfl_xor(s1, 8);
        s1 += __shfl_xor(s1, 16);
        s1 += __shfl_xor(s1, 32);
        float inv1 = 1.f / s1;
        float m2 = -INFINITY;
#pragma unroll
        for (int i = 0; i < 8; ++i) {
          int j = slot + 8*i;
          if (j < deg) {
            float pj = __shfl(myppr, j);
            float v = 0.5f * expf(Preg[i] - m1) * inv1 + 0.5f * pj;
            Preg[i] = v;
            m2 = fmaxf(m2, v);
          }
        }
        m2 = fmaxf(m2, __shfl_xor(m2, 8));
        m2 = fmaxf(m2, __shfl_xor(m2, 16));
        m2 = fmaxf(m2, __shfl_xor(m2, 32));
        float s2 = 0.f;
#pragma unroll
        for (int i = 0; i < 8; ++i)
          s2 += (slot + 8*i < deg) ? expf(Preg[i] - m2) : 0.f;
        s2 += __shfl_xor(s2, 8);
        s2 += __shfl_xor(s2, 16);
        s2 += __shfl_xor(s2, 32);
        float inv2 = 1.f / s2;
#pragma unroll
        for (int i = 0; i < 8; ++i)
          if (slot + 8*i < deg) Preg[i] = expf(Preg[i] - m2) * inv2;
      }

      // ---- phase 3: u_new ----
      float acc[8] = {0.f, 0.f, 0.f, 0.f, 0.f, 0.f, 0.f, 0.f};
#pragma unroll
      for (int j = 0; j < CAPR; ++j) {
        if (j < deg) {
          float w = __shfl(Preg[j >> 3], ((j & 7) << 3) | cap);
          float zf[8];
          unpack8(zreg[j], zf);
#pragma unroll
          for (int q = 0; q < 8; ++q) acc[q] += w * zf[q];
        }
      }
      for (int j = CAPR; j < deg; ++j) {
        int hi = j >> 3;
        float pr = Preg[1];
        if      (hi == 2) pr = Preg[2];
        else if (hi == 3) pr = Preg[3];
        else if (hi == 4) pr = Preg[4];
        else if (hi == 5) pr = Preg[5];
        else if (hi == 6) pr = Preg[6];
        else if (hi == 7) pr = Preg[7];
        float w = __shfl(pr, ((j & 7) << 3) | cap);
        int c = __shfl(mycol, j);
        uint4 zz = *(const uint4*)(xn + (size_t)c * 512 + lane * 8);
        float zf[8];
        unpack8(zz, zf);
#pragma unroll
        for (int q = 0; q < 8; ++q) acc[q] += w * zf[q];
      }
      if (it < 2) {
        float ss = 0.f;
#pragma unroll
        for (int q = 0; q < 8; ++q) ss += acc[q] * acc[q];
        ss += __shfl_xor(ss, 1);
        ss += __shfl_xor(ss, 2);
        ss += __shfl_xor(ss, 4);
        float sc = 1.f / fmaxf(sqrtf(ss), 1e-12f);
#pragma unroll
        for (int q = 0; q < 8; ++q) acc[q] *= sc;
      }
#pragma unroll
      for (int q = 0; q < 8; ++q) uf[q] = acc[q];
    }
  }

  // output: ub = bf16(relu(u)) for the MLP GEMM
  uint4 pk;
  pk.x = (u32)f2bf(fmaxf(uf[0], 0.f)) | ((u32)f2bf(fmaxf(uf[1], 0.f)) << 16);
  pk.y = (u32)f2bf(fmaxf(uf[2], 0.f)) | ((u32)f2bf(fmaxf(uf[3], 0.f)) << 16);
  pk.z = (u32)f2bf(fmaxf(uf[4], 0.f)) | ((u32)f2bf(fmaxf(uf[5], 0.f)) << 16);
  pk.w = (u32)f2bf(fmaxf(uf[6], 0.f)) | ((u32)f2bf(fmaxf(uf[7], 0.f)) << 16);
  *(uint4*)(ub + (size_t)t * 512 + lane * 8) = pk;
}

// ---------- kernel 5: logits = ub @ Bt2^T + mb; fused log_softmax epilogue. ----------
__global__ __launch_bounds__(256) void mlp_gemm(
    const u16* __restrict__ ub, const u16* __restrict__ Bt2,
    const float* __restrict__ mb, float* __restrict__ out) {
  const int wid = threadIdx.x >> 6, lane = threadIdx.x & 63;
  const int quad = lane >> 4, l16 = lane & 15;
  const int m0 = blockIdx.x * 64 + wid * 16;

  floatx4 acc[4];
#pragma unroll
  for (int ni = 0; ni < 4; ++ni) acc[ni] = (floatx4){0.f, 0.f, 0.f, 0.f};

#pragma unroll 4
  for (int kk = 0; kk < 512; kk += 32) {
    short8 af = *(const short8*)(ub + (size_t)(m0 + l16) * 512 + kk + quad * 8);
#pragma unroll
    for (int ni = 0; ni < 4; ++ni) {
      short8 bf = *(const short8*)(Bt2 + (size_t)(ni * 16 + l16) * 512 + kk + quad * 8);
      acc[ni] = __builtin_amdgcn_mfma_f32_16x16x32_bf16(af, bf, acc[ni], 0, 0, 0);
    }
  }

#pragma unroll
  for (int r = 0; r < 4; ++r) {
    int t = m0 + quad * 4 + r;
    float v[4];
    float mx = -INFINITY;
#pragma unroll
    for (int ni = 0; ni < 4; ++ni) {
      int c = ni * 16 + l16;
      float lg = (c < NCLS) ? (acc[ni][r] + mb[c]) : -INFINITY;
      v[ni] = lg;
      mx = fmaxf(mx, lg);
    }
    mx = fmaxf(mx, __shfl_xor(mx, 1));
    mx = fmaxf(mx, __shfl_xor(mx, 2));
    mx = fmaxf(mx, __shfl_xor(mx, 4));
    mx = fmaxf(mx, __shfl_xor(mx, 8));
    float se = 0.f;
#pragma unroll
    for (int ni = 0; ni < 4; ++ni) {
      int c = ni * 16 + l16;
      if (c < NCLS) se += expf(v[ni] - mx);
    }
    se += __shfl_xor(se, 1);
    se += __shfl_xor(se, 2);
    se += __shfl_xor(se, 4);
    se += __shfl_xor(se, 8);
    float lse = mx + logf(se);
#pragma unroll
    for (int ni = 0; ni < 4; ++ni) {
      int c = ni * 16 + l16;
      if (c < NCLS) out[(size_t)t * NCLS + c] = v[ni] - lse;
    }
  }
}

// ---------- launch ----------
extern "C" void kernel_launch(void* const* d_in, const int* in_sizes, int n_in,
                              void* d_out, int out_size, void* d_ws, size_t ws_size,
                              hipStream_t stream) {
  const float* x_nb  = (const float*)d_in[0];
  const float* ppr   = (const float*)d_in[1];
  const float* pca_w = (const float*)d_in[2];
  const float* pca_b = (const float*)d_in[3];
  const float* mlp_w = (const float*)d_in[4];
  const float* mlp_b = (const float*)d_in[5];
  const int* row_idx = (const int*)d_in[6];
  const int* col_idx = (const int*)d_in[7];
  float* out = (float*)d_out;

  char* ws = (char*)d_ws;
  const size_t OFF_BT   = 0;                                  // 512 KB
  const size_t OFF_BT2  = 512 * 1024;                         // 64 KB
  const size_t OFF_PPRN = 640 * 1024;                         // E*4 = 512 KB
  const size_t OFF_OFFS = 1152 * 1024;                        // (T+1)*4
  const size_t OFF_XN   = 1280 * 1024;                        // NB*512*2 = 102.4 MB
  const size_t OFF_UB   = OFF_XN + (size_t)NB_N * 512 * 2;    // T*512*2 = 16.8 MB
  u16*   Bt   = (u16*)(ws + OFF_BT);
  u16*   Bt2  = (u16*)(ws + OFF_BT2);
  float* pprn = (float*)(ws + OFF_PPRN);
  int*   offs = (int*)(ws + OFF_OFFS);
  u16*   xn   = (u16*)(ws + OFF_XN);
  u16*   ub   = (u16*)(ws + OFF_UB);

  conv_bt<<<1024, 256, 0, stream>>>(pca_w, Bt);
  conv_bt2<<<128, 256, 0, stream>>>(mlp_w, Bt2);
  build_offs<<<512, 256, 0, stream>>>(row_idx, offs);
  ppr_sm<<<64, 256, 0, stream>>>(ppr, offs, pprn);

  // 196 groups of 32 blocks: group g covers m-tiles 8g..8g+7 x all 4 n-tiles
  gemm_pca<<<196 * 32, 256, 0, stream>>>(x_nb, Bt, pca_b, xn);

  fused_all<<<T_N / 2, 128, 0, stream>>>(xn, col_idx, offs, pprn, ub);

  mlp_gemm<<<256, 256, 0, stream>>>(ub, Bt2, mlp_b, out);
}

// Round 10
// 450.186 us; speedup vs baseline: 1.0288x; 1.0288x over previous
//
#include <hip/hip_runtime.h>
#include <cstdint>
#include <cstddef>

// Problem constants (fixed by reference file)
#define NB_N 100000
#define E_N  131072
#define T_N  16384
#define D_N  512
#define NCLS 40
#define NTILES 782          // ceil(100000/128); 782*128 = 100096
#define CAPR 12             // legacy-path register z-cache edges/target

typedef unsigned short u16;
typedef unsigned int   u32;
typedef __attribute__((ext_vector_type(8))) short  short8;   // 8 bf16 (4 VGPRs)
typedef __attribute__((ext_vector_type(4))) float  floatx4;  // MFMA accumulator

// ---------- bf16 helpers (manual, RNE) ----------
__device__ __forceinline__ u16 f2bf(float f) {
  u32 u = __float_as_uint(f);
  return (u16)((u + 0x7fffu + ((u >> 16) & 1u)) >> 16);
}
__device__ __forceinline__ void unpack8(uint4 z, float* f) {
  f[0] = __uint_as_float(z.x << 16);
  f[1] = __uint_as_float(z.x & 0xffff0000u);
  f[2] = __uint_as_float(z.y << 16);
  f[3] = __uint_as_float(z.y & 0xffff0000u);
  f[4] = __uint_as_float(z.z << 16);
  f[5] = __uint_as_float(z.z & 0xffff0000u);
  f[6] = __uint_as_float(z.w << 16);
  f[7] = __uint_as_float(z.w & 0xffff0000u);
}
__device__ __forceinline__ void gload_lds16(const void* g, void* s) {
  __builtin_amdgcn_global_load_lds(
      (const __attribute__((address_space(1))) unsigned int*)g,
      (__attribute__((address_space(3))) unsigned int*)s, 16, 0, 0);
}
// packed f32x2 -> bf16x2 (RNE), hw instruction; bit-identical to f2bf on finite vals
__device__ __forceinline__ u32 cvtpk_bf16(float lo, float hi) {
  u32 r;
  asm("v_cvt_pk_bf16_f32 %0, %1, %2" : "=v"(r) : "v"(lo), "v"(hi));
  return r;
}

// ---------- kernel 0: transpose+convert pca_w (K,N) f32 -> Bt (N,K) bf16 ----------
__global__ void conv_bt(const float* __restrict__ w, u16* __restrict__ Bt) {
  int i = blockIdx.x * 256 + threadIdx.x;       // i over 512*512, i = n*512+k
  int n = i >> 9, k = i & 511;
  Bt[i] = f2bf(w[k * 512 + n]);
}

// ---------- kernel 0b: transpose+convert mlp_w (512,40) f32 -> Bt2 (64,512) bf16, zero-pad ----
__global__ void conv_bt2(const float* __restrict__ w, u16* __restrict__ Bt2) {
  int i = blockIdx.x * 256 + threadIdx.x;       // 64*512 elements, i = n*512+k
  int n = i >> 9, k = i & 511;
  Bt2[i] = (n < NCLS) ? f2bf(w[k * NCLS + n]) : (u16)0;
}

// ---------- kernel 1: CSR offsets from sorted row_idx ----------
__global__ void build_offs(const int* __restrict__ rowi, int* __restrict__ offs) {
  int e = blockIdx.x * 256 + threadIdx.x;
  if (e >= E_N) return;
  int r  = rowi[e];
  int rp = (e == 0) ? -1 : rowi[e - 1];
  for (int t = rp + 1; t <= r; ++t) offs[t] = e;
  if (e == E_N - 1)
    for (int t = r + 1; t <= T_N; ++t) offs[t] = E_N;
}

// ---------- kernel 2: segment softmax of ppr ----------
__global__ void ppr_sm(const float* __restrict__ ppr, const int* __restrict__ offs,
                       float* __restrict__ pprn) {
  int t = blockIdx.x * 256 + threadIdx.x;       // T_N threads
  int s = offs[t], en = offs[t + 1];
  if (s >= en) return;
  float m = -INFINITY;
  for (int e = s; e < en; ++e) m = fmaxf(m, ppr[e]);
  float sum = 0.f;
  for (int e = s; e < en; ++e) sum += expf(ppr[e] - m);
  float inv = 1.f / sum;
  for (int e = s; e < en; ++e) pprn[e] = expf(ppr[e] - m) * inv;
}

// ---------- kernel 3: bf16 MFMA GEMM x = relu(x_nb @ pca_w + b), per-capsule l2norm,
//            writes xn bf16.
//            R12 config (PROVEN 130.5us, R8): 128x128, 256 thr, BK=64, 3 blocks/CU,
//            reg-staged A (single-buf) + dbuf DMA B, counted-vmcnt 2-barrier
//            schedule with B issued 2 steps ahead. R13's 4-blocks/64-row tile
//            regressed (137us) -> occupancy lever saturated at 3 blocks. ----------
__global__ __launch_bounds__(256, 3) void gemm_pca(
    const float* __restrict__ A,    // x_nb (NB,512) f32
    const u16*   __restrict__ Bt,   // (512,512) bf16, n-major (pre-transposed)
    const float* __restrict__ bias, // (512,)
    u16*         __restrict__ xn) { // (NB,512) bf16, normalized
  __shared__ u16 SMEM[24576];       // 48 KB: As 128x64 (16KB) | Bs dbuf 2x 128x64 (32KB)
  u16* As = SMEM;
  u16* Bs = SMEM + 8192;            // buffer b at Bs + b*8192
  const int tid  = threadIdx.x;
  const int wid  = tid >> 6, lane = tid & 63;
  const int quad = lane >> 4, l16 = lane & 15;
  // XCD-grouped decode: b = 32g + 8n + mlow -> mt = 8g+mlow, n in {0..3}.
  const int b  = blockIdx.x;
  const int mt = (b & 7) | ((b >> 5) << 3);
  if (mt >= NTILES) return;
  const int m0 = mt * 128;
  const int n0 = ((b >> 3) & 3) * 128;
  const int wm = (wid >> 1) * 64;
  const int wn = (wid & 1) * 64;
  const int sw = l16 & 7;           // per-lane chunk swizzle for frag reads

  floatx4 acc[4][4];
#pragma unroll
  for (int i = 0; i < 4; ++i)
#pragma unroll
    for (int j = 0; j < 4; ++j) acc[i][j] = (floatx4){0.f, 0.f, 0.f, 0.f};

  float4 pa0[4], pa1[4];            // in-flight A regs: 4 units x 2 float4 (8 loads)

  auto issueA = [&](int k0) {
#pragma unroll
    for (int j = 0; j < 4; ++j) {
      int ci = j * 256 + tid;                 // 1024 units: row=ci>>3, kc=ci&7
      int row = ci >> 3, kc = ci & 7;
      int gm = m0 + row;
      if (gm > NB_N - 1) gm = NB_N - 1;       // clamp: exact vmcnt, rows never stored
      const float* src = A + (size_t)gm * 512 + k0 + kc * 8;
      pa0[j] = *(const float4*)(src);
      pa1[j] = *(const float4*)(src + 4);
    }
  };
  auto writeA = [&]() {
#pragma unroll
    for (int j = 0; j < 4; ++j) {
      int ci = j * 256 + tid;
      int row = ci >> 3, kc = ci & 7;
      uint4 pk;
      pk.x = cvtpk_bf16(pa0[j].x, pa0[j].y);
      pk.y = cvtpk_bf16(pa0[j].z, pa0[j].w);
      pk.z = cvtpk_bf16(pa1[j].x, pa1[j].y);
      pk.w = cvtpk_bf16(pa1[j].z, pa1[j].w);
      int dc = kc ^ (row & 7);                // dest-side swizzle
      *(uint4*)(&As[(size_t)(row * 8 + dc) * 8]) = pk;
    }
  };
  auto issueB = [&](int k0, u16* dstB) {
#pragma unroll
    for (int j = 0; j < 4; ++j) {
      int ci  = j * 256 + wid * 64 + lane;    // 1024 chunks
      int row = ci >> 3;
      int kcs = (lane & 7) ^ ((lane >> 3) & 7);
      gload_lds16(Bt + (size_t)(n0 + row) * 512 + k0 + kcs * 8,
                  &dstB[(size_t)(j * 256 + wid * 64) * 8]);
    }
  };

  // ---- prologue: A0, B0, B1 staged; A1 in flight ----
  issueA(0);                          // A0: 8 loads
  issueB(0, Bs);                      // B0 -> slot 0 (4 DMA)
  issueB(64, Bs + 8192);              // B1 -> slot 1 (4 DMA)
  writeA();                           // implicit vmcnt(8): A0 done; B0,B1 in flight
  issueA(64);                         // A1: 8 loads
  asm volatile("s_waitcnt vmcnt(12) lgkmcnt(0)" ::: "memory");  // drain B0; keep B1+A1
  __builtin_amdgcn_s_barrier();
  __builtin_amdgcn_sched_barrier(0);

  // ---- main loop: 8 k-steps, 2 barriers/step; B issued 2 steps ahead ----
#pragma unroll
  for (int s = 0; s < 8; ++s) {
    const int cs = s & 1;
    const u16* Bsc = Bs + cs * 8192;
    // compute step s (reads As + Bsc)
#pragma unroll
    for (int kk = 0; kk < 64; kk += 32) {
      short8 af[4], bf[4];
#pragma unroll
      for (int mi = 0; mi < 4; ++mi) {
        int c = (kk >> 3) + quad;
        af[mi] = *(const short8*)(&As[(wm + mi * 16 + l16) * 64 + ((c ^ sw) << 3)]);
      }
#pragma unroll
      for (int ni = 0; ni < 4; ++ni) {
        int c = (kk >> 3) + quad;
        bf[ni] = *(const short8*)(&Bsc[(wn + ni * 16 + l16) * 64 + ((c ^ sw) << 3)]);
      }
#pragma unroll
      for (int mi = 0; mi < 4; ++mi)
#pragma unroll
        for (int ni = 0; ni < 4; ++ni)
          acc[mi][ni] = __builtin_amdgcn_mfma_f32_16x16x32_bf16(af[mi], bf[ni],
                                                                acc[mi][ni], 0, 0, 0);
    }
    // barrier 1: all waves done READING As + Bs[cs] (slot cs now free)
    __builtin_amdgcn_s_barrier();
    __builtin_amdgcn_sched_barrier(0);
    if (s + 1 < 8) {
      if (s + 2 < 8) issueB((s + 2) * 64, Bs + cs * 8192);  // slot (s+2)&1 == cs
      writeA();                       // implicit wait: A(s+1) done -> B(s+1) (older) done
      if (s + 2 < 8) {
        issueA((s + 2) * 64);         // refill A regs (8 loads)
        asm volatile("s_waitcnt vmcnt(12) lgkmcnt(0)" ::: "memory");  // keep B(s+2)+A(s+2)
      } else {
        asm volatile("s_waitcnt vmcnt(0) lgkmcnt(0)" ::: "memory");   // tail: drain all
      }
      __builtin_amdgcn_s_barrier();   // barrier 2: As written + B(s+1) resident
      __builtin_amdgcn_sched_barrier(0);
    }
  }
  __syncthreads();                    // all compute done before Os overwrites SMEM

  // epilogue: +bias, relu, per-capsule (64-col) l2norm -> LDS tile -> full-line stores
  u16* Os = SMEM;                     // 128x128 u16 = 32 KB (As/Bs dead)
#pragma unroll
  for (int mi = 0; mi < 4; ++mi) {
#pragma unroll
    for (int r = 0; r < 4; ++r) {
      int lrow = wm + mi * 16 + quad * 4 + r;
      float v[4];
      float ss = 0.f;
#pragma unroll
      for (int ni = 0; ni < 4; ++ni) {
        int n  = n0 + wn + ni * 16 + l16;
        float x = acc[mi][ni][r] + bias[n];
        x = fmaxf(x, 0.f);
        v[ni] = x;
        ss += x * x;
      }
      ss += __shfl_xor(ss, 1);
      ss += __shfl_xor(ss, 2);
      ss += __shfl_xor(ss, 4);
      ss += __shfl_xor(ss, 8);
      float sc = 1.f / fmaxf(sqrtf(ss), 1e-12f);
#pragma unroll
      for (int ni = 0; ni < 4; ++ni)
        Os[lrow * 128 + wn + ni * 16 + l16] = f2bf(v[ni] * sc);
    }
  }
  __syncthreads();
#pragma unroll
  for (int c8 = 0; c8 < 8; ++c8) {    // 2048 16B-chunks, 8 per thread
    int idx = c8 * 256 + tid;
    int row = idx >> 4, chk = idx & 15;
    int gm = m0 + row;
    if (gm < NB_N) {
      uint4 val = *(const uint4*)(&Os[row * 128 + chk * 8]);
      *(uint4*)(xn + (size_t)gm * 512 + n0 + chk * 8) = val;
    }
  }
}

// ---------- fast-path helpers for kernel 4 ----------
// matvec in coefficient space: e_i = sum_j G[i][j] * w[j], rows i0 / i0+8 per lane.
// w[c][j] lives at lane (c*8 | (j&7)), register w0 (j<8) / w1 (j>=8).
__device__ __forceinline__ void matvec16(const float (&g0)[16], const float (&g1)[16],
                                         float w0, float w1, int base,
                                         float& e0, float& e1) {
  e0 = 0.f; e1 = 0.f;
#pragma unroll
  for (int j = 0; j < 8; ++j) {
    float wj = __shfl(w0, base | j);
    e0 += g0[j] * wj;
    e1 += g1[j] * wj;
  }
#pragma unroll
  for (int j = 0; j < 8; ++j) {
    float wj = __shfl(w1, base | j);
    e0 += g0[8 + j] * wj;
    e1 += g1[8 + j] * wj;
  }
}

// segment softmax over edges of one capsule: values d0 (edge i0), d1 (edge i0+8),
// reduction across the 8 lanes of the capsule group (xor 1,2,4). Invalid -> 0.
__device__ __forceinline__ void segsm2(float& d0, float& d1, bool v0, bool v1) {
  float m = fmaxf(v0 ? d0 : -INFINITY, v1 ? d1 : -INFINITY);
  m = fmaxf(m, __shfl_xor(m, 1));
  m = fmaxf(m, __shfl_xor(m, 2));
  m = fmaxf(m, __shfl_xor(m, 4));
  float e0 = v0 ? expf(d0 - m) : 0.f;
  float e1 = v1 ? expf(d1 - m) : 0.f;
  float s = e0 + e1;
  s += __shfl_xor(s, 1);
  s += __shfl_xor(s, 2);
  s += __shfl_xor(s, 4);
  float inv = 1.f / s;
  d0 = e0 * inv;
  d1 = e1 * inv;
}

// ---------- kernel 4: ALL routing (init + 3 rounds), one target per wave.
//            FAST PATH (deg<=16, ~99.6%): per-capsule Gram matrices via MFMA;
//            routing in deg-dim coefficient space.
//            R14: z-rows stashed in LDS during the Gram gather (chunk-XOR
//            swizzle: write chunk k at k^(row&7), read back the same way) so
//            the final reconstruction u = sum_j P2_j z_j reads LDS instead of
//            re-gathering ~256 MB of random rows from global (the wave already
//            held every byte in registers). Same-wave write->read: no barrier.
//            LEGACY PATH (deg>16): edge loop, unchanged. ----------
__global__ __launch_bounds__(128, 4) void fused_all(
    const u16* __restrict__ xn, const int* __restrict__ coli,
    const int* __restrict__ offs, const float* __restrict__ pprn,
    u16* __restrict__ ub) {
  // per-wave Gram staging (16x16 + 4 pad per capsule) + per-wave z stash
  __shared__ __align__(16) float Glds[2][8 * 260];   // 16.6 KB
  __shared__ __align__(16) u16   Zlds[2][16][512];   // 32 KB
  const int lane = threadIdx.x & 63;
  const int wv = threadIdx.x >> 6;
  const int t = blockIdx.x * 2 + wv;
  const int s = offs[t], en = offs[t + 1];
  int deg = en - s;
  if (deg > 64) deg = 64;           // Poisson(8): max over 16k targets ~27

  int   mycol = (lane < deg) ? coli[s + lane] : 0;
  float myppr = (lane < deg) ? pprn[s + lane] : 0.f;

  float uf[8] = {0.f, 0.f, 0.f, 0.f, 0.f, 0.f, 0.f, 0.f};

  if (deg <= 16) {
    // ================= fast path =================
    float* G = Glds[wv];
    u16 (*Z)[512] = Zlds[wv];
    // 1) gather z fragments (lane: edge=lane&15, k-chunk=lane>>4), stash to LDS,
    //    and build Grams. Chunk ids (16B units in the 1KB row): f0 -> c*8+kq,
    //    f1 -> c*8+4+kq; stored XORed with (row&7) -> 2-way-free writes.
    const int esrc = lane & 15, kq = lane >> 4;
    const int swz = esrc & 7;
    int ce = __shfl(mycol, esrc);                 // edges >= deg read row 0 (masked later)
    const u16* zb = xn + (size_t)ce * 512 + kq * 8;
    floatx4 gram[8];
#pragma unroll
    for (int c = 0; c < 8; ++c) {
      short8 f0 = *(const short8*)(zb + c * 64);
      short8 f1 = *(const short8*)(zb + c * 64 + 32);
      *(short8*)(&Z[esrc][((c * 8 + kq) ^ swz) * 8])     = f0;
      *(short8*)(&Z[esrc][((c * 8 + 4 + kq) ^ swz) * 8]) = f1;
      floatx4 gg = (floatx4){0.f, 0.f, 0.f, 0.f};
      gg = __builtin_amdgcn_mfma_f32_16x16x32_bf16(f0, f0, gg, 0, 0, 0);
      gg = __builtin_amdgcn_mfma_f32_16x16x32_bf16(f1, f1, gg, 0, 0, 0);
      gram[c] = gg;
    }
    // 2) D layout: lane holds G[i=kq*4+r][j=esrc]; store as [c][esrc][kq*4+r]
#pragma unroll
    for (int c = 0; c < 8; ++c)
      *(float4*)&G[c * 260 + esrc * 16 + kq * 4] = *(float4*)&gram[c];
    // 3) lane (c=lane>>3, i0=lane&7) loads rows i0 and i0+8 of its capsule's Gram
    const int cc = lane >> 3, i0 = lane & 7;
    const int base = lane & 56;                   // == cc*8, bpermute broadcast base
    float g0[16], g1[16];
    {
      const float* r0 = &G[cc * 260 + i0 * 16];
      const float* r1 = &G[cc * 260 + (i0 + 8) * 16];
#pragma unroll
      for (int ch = 0; ch < 4; ++ch) {
        float4 a = *(const float4*)(r0 + ch * 4);
        float4 b = *(const float4*)(r1 + ch * 4);
        g0[ch * 4 + 0] = a.x; g0[ch * 4 + 1] = a.y;
        g0[ch * 4 + 2] = a.z; g0[ch * 4 + 3] = a.w;
        g1[ch * 4 + 0] = b.x; g1[ch * 4 + 1] = b.y;
        g1[ch * 4 + 2] = b.z; g1[ch * 4 + 3] = b.w;
      }
    }
    const bool v0 = i0 < deg, v1 = (i0 + 8) < deg;
    float pr0 = __shfl(myppr, i0);                // ppr[i0], 0 if invalid
    float pr1 = __shfl(myppr, i0 + 8);

    // init logits: d = G . ppr  (== <u0, z_i>, u0 = sum ppr_j z_j, unnormalized)
    float d0, d1;
    matvec16(g0, g1, pr0, pr1, base, d0, d1);

    float w0 = 0.f, w1 = 0.f;
#pragma unroll
    for (int it = 0; it < 3; ++it) {
      segsm2(d0, d1, v0, v1);                     // first segment softmax
      d0 = 0.5f * d0 + 0.5f * pr0;                // blend with pprn (invalid: 0+0)
      d1 = 0.5f * d1 + 0.5f * pr1;
      segsm2(d0, d1, v0, v1);                     // second segment softmax -> P
      w0 = d0; w1 = d1;                           // coefficients (invalid == 0)
      if (it < 2) {
        // e = G.P serves both the l2norm (||u||^2 = P^T G P) and next logits
        float e0, e1;
        matvec16(g0, g1, w0, w1, base, e0, e1);
        float nv = w0 * e0 + w1 * e1;
        nv += __shfl_xor(nv, 1);
        nv += __shfl_xor(nv, 2);
        nv += __shfl_xor(nv, 4);
        float invn = 1.f / fmaxf(sqrtf(nv), 1e-12f);
        d0 = e0 * invn;
        d1 = e1 * invn;
      }
    }

    // final reconstruction from the LDS stash: lane reads chunk lane^(j&7) of
    // row j (same swizzle as the write). Full-row reads = bandwidth-floor.
#pragma unroll
    for (int j = 0; j < 16; ++j) {
      if (j < deg) {                              // wave-uniform branch
        float wj = __shfl((j < 8) ? w0 : w1, base | (j & 7));
        uint4 zz = *(const uint4*)(&Z[j][(lane ^ (j & 7)) * 8]);
        float zf[8];
        unpack8(zz, zf);
#pragma unroll
        for (int q = 0; q < 8; ++q) uf[q] += wj * zf[q];
      }
    }
  } else {
    // ================= legacy path (deg > 16, ~0.4% of targets) =================
    const int cap = lane >> 3;
    const int slot = lane >> 3;

    uint4 zreg[CAPR];
#pragma unroll
    for (int j = 0; j < CAPR; ++j) {
      if (j < deg) {
        int c = __shfl(mycol, j);
        zreg[j] = *(const uint4*)(xn + (size_t)c * 512 + lane * 8);
      }
    }

    // init: u0 = sum_e pprn_e * z_e
#pragma unroll
    for (int j = 0; j < CAPR; ++j) {
      if (j < deg) {
        float w = __shfl(myppr, j);
        float zf[8];
        unpack8(zreg[j], zf);
#pragma unroll
        for (int q = 0; q < 8; ++q) uf[q] += w * zf[q];
      }
    }
    for (int j = CAPR; j < deg; ++j) {
      float w = __shfl(myppr, j);
      int c = __shfl(mycol, j);
      uint4 zz = *(const uint4*)(xn + (size_t)c * 512 + lane * 8);
      float zf[8];
      unpack8(zz, zf);
#pragma unroll
      for (int q = 0; q < 8; ++q) uf[q] += w * zf[q];
    }

    float Preg[8];

    for (int it = 0; it < 3; ++it) {
      // ---- phase 1: capsule logits ----
#pragma unroll
      for (int j = 0; j < CAPR; ++j) {
        if (j < deg) {
          float zf[8];
          unpack8(zreg[j], zf);
          float d = uf[0]*zf[0] + uf[1]*zf[1] + uf[2]*zf[2] + uf[3]*zf[3] +
                    uf[4]*zf[4] + uf[5]*zf[5] + uf[6]*zf[6] + uf[7]*zf[7];
          d += __shfl_xor(d, 1);
          d += __shfl_xor(d, 2);
          d += __shfl_xor(d, 4);
          float dc = __shfl(d, (lane & 7) << 3);
          if (slot == (j & 7)) Preg[j >> 3] = dc;
        }
      }
      for (int j = CAPR; j < deg; ++j) {
        int c = __shfl(mycol, j);
        uint4 zz = *(const uint4*)(xn + (size_t)c * 512 + lane * 8);
        float zf[8];
        unpack8(zz, zf);
        float d = uf[0]*zf[0] + uf[1]*zf[1] + uf[2]*zf[2] + uf[3]*zf[3] +
                  uf[4]*zf[4] + uf[5]*zf[5] + uf[6]*zf[6] + uf[7]*zf[7];
        d += __shfl_xor(d, 1);
        d += __shfl_xor(d, 2);
        d += __shfl_xor(d, 4);
        float dc = __shfl(d, (lane & 7) << 3);
        if (slot == (j & 7)) {
          int hi = j >> 3;
          if      (hi == 1) Preg[1] = dc;
          else if (hi == 2) Preg[2] = dc;
          else if (hi == 3) Preg[3] = dc;
          else if (hi == 4) Preg[4] = dc;
          else if (hi == 5) Preg[5] = dc;
          else if (hi == 6) Preg[6] = dc;
          else if (hi == 7) Preg[7] = dc;
        }
      }

      // ---- phase 2: segsm -> blend -> segsm ----
      {
        float m1 = -INFINITY;
#pragma unroll
        for (int i = 0; i < 8; ++i)
          m1 = (slot + 8*i < deg) ? fmaxf(m1, Preg[i]) : m1;
        m1 = fmaxf(m1, __shfl_xor(m1, 8));
        m1 = fmaxf(m1, __shfl_xor(m1, 16));
        m1 = fmaxf(m1, __shfl_xor(m1, 32));
        float s1 = 0.f;
#pragma unroll
        for (int i = 0; i < 8; ++i)
          s1 += (slot + 8*i < deg) ? expf(Preg[i] - m1) : 0.f;
        s1 += __shfl_xor(s1, 8);
        s1 += __shfl_xor(s1, 16);
        s1 += __shfl_xor(s1, 32);
        float inv1 = 1.f / s1;
        float m2 = -INFINITY;
#pragma unroll
        for (int i = 0; i < 8; ++i) {
          int j = slot + 8*i;
          if (j < deg) {
            float pj = __shfl(myppr, j);
            float v = 0.5f * expf(Preg[i] - m1) * inv1 + 0.5f * pj;
            Preg[i] = v;
            m2 = fmaxf(m2, v);
          }
        }
        m2 = fmaxf(m2, __shfl_xor(m2, 8));
        m2 = fmaxf(m2, __shfl_xor(m2, 16));
        m2 = fmaxf(m2, __shfl_xor(m2, 32));
        float s2 = 0.f;
#pragma unroll
        for (int i = 0; i < 8; ++i)
          s2 += (slot + 8*i < deg) ? expf(Preg[i] - m2) : 0.f;
        s2 += __shfl_xor(s2, 8);
        s2 += __shfl_xor(s2, 16);
        s2 += __shfl_xor(s2, 32);
        float inv2 = 1.f / s2;
#pragma unroll
        for (int i = 0; i < 8; ++i)
          if (slot + 8*i < deg) Preg[i] = expf(Preg[i] - m2) * inv2;
      }

      // ---- phase 3: u_new ----
      float acc[8] = {0.f, 0.f, 0.f, 0.f, 0.f, 0.f, 0.f, 0.f};
#pragma unroll
      for (int j = 0; j < CAPR; ++j) {
        if (j < deg) {
          float w = __shfl(Preg[j >> 3], ((j & 7) << 3) | cap);
          float zf[8];
          unpack8(zreg[j], zf);
#pragma unroll
          for (int q = 0; q < 8; ++q) acc[q] += w * zf[q];
        }
      }
      for (int j = CAPR; j < deg; ++j) {
        int hi = j >> 3;
        float pr = Preg[1];
        if      (hi == 2) pr = Preg[2];
        else if (hi == 3) pr = Preg[3];
        else if (hi == 4) pr = Preg[4];
        else if (hi == 5) pr = Preg[5];
        else if (hi == 6) pr = Preg[6];
        else if (hi == 7) pr = Preg[7];
        float w = __shfl(pr, ((j & 7) << 3) | cap);
        int c = __shfl(mycol, j);
        uint4 zz = *(const uint4*)(xn + (size_t)c * 512 + lane * 8);
        float zf[8];
        unpack8(zz, zf);
#pragma unroll
        for (int q = 0; q < 8; ++q) acc[q] += w * zf[q];
      }
      if (it < 2) {
        float ss = 0.f;
#pragma unroll
        for (int q = 0; q < 8; ++q) ss += acc[q] * acc[q];
        ss += __shfl_xor(ss, 1);
        ss += __shfl_xor(ss, 2);
        ss += __shfl_xor(ss, 4);
        float sc = 1.f / fmaxf(sqrtf(ss), 1e-12f);
#pragma unroll
        for (int q = 0; q < 8; ++q) acc[q] *= sc;
      }
#pragma unroll
      for (int q = 0; q < 8; ++q) uf[q] = acc[q];
    }
  }

  // output: ub = bf16(relu(u)) for the MLP GEMM
  uint4 pk;
  pk.x = (u32)f2bf(fmaxf(uf[0], 0.f)) | ((u32)f2bf(fmaxf(uf[1], 0.f)) << 16);
  pk.y = (u32)f2bf(fmaxf(uf[2], 0.f)) | ((u32)f2bf(fmaxf(uf[3], 0.f)) << 16);
  pk.z = (u32)f2bf(fmaxf(uf[4], 0.f)) | ((u32)f2bf(fmaxf(uf[5], 0.f)) << 16);
  pk.w = (u32)f2bf(fmaxf(uf[6], 0.f)) | ((u32)f2bf(fmaxf(uf[7], 0.f)) << 16);
  *(uint4*)(ub + (size_t)t * 512 + lane * 8) = pk;
}

// ---------- kernel 5: logits = ub @ Bt2^T + mb; fused log_softmax epilogue. ----------
__global__ __launch_bounds__(256) void mlp_gemm(
    const u16* __restrict__ ub, const u16* __restrict__ Bt2,
    const float* __restrict__ mb, float* __restrict__ out) {
  const int wid = threadIdx.x >> 6, lane = threadIdx.x & 63;
  const int quad = lane >> 4, l16 = lane & 15;
  const int m0 = blockIdx.x * 64 + wid * 16;

  floatx4 acc[4];
#pragma unroll
  for (int ni = 0; ni < 4; ++ni) acc[ni] = (floatx4){0.f, 0.f, 0.f, 0.f};

#pragma unroll 4
  for (int kk = 0; kk < 512; kk += 32) {
    short8 af = *(const short8*)(ub + (size_t)(m0 + l16) * 512 + kk + quad * 8);
#pragma unroll
    for (int ni = 0; ni < 4; ++ni) {
      short8 bf = *(const short8*)(Bt2 + (size_t)(ni * 16 + l16) * 512 + kk + quad * 8);
      acc[ni] = __builtin_amdgcn_mfma_f32_16x16x32_bf16(af, bf, acc[ni], 0, 0, 0);
    }
  }

#pragma unroll
  for (int r = 0; r < 4; ++r) {
    int t = m0 + quad * 4 + r;
    float v[4];
    float mx = -INFINITY;
#pragma unroll
    for (int ni = 0; ni < 4; ++ni) {
      int c = ni * 16 + l16;
      float lg = (c < NCLS) ? (acc[ni][r] + mb[c]) : -INFINITY;
      v[ni] = lg;
      mx = fmaxf(mx, lg);
    }
    mx = fmaxf(mx, __shfl_xor(mx, 1));
    mx = fmaxf(mx, __shfl_xor(mx, 2));
    mx = fmaxf(mx, __shfl_xor(mx, 4));
    mx = fmaxf(mx, __shfl_xor(mx, 8));
    float se = 0.f;
#pragma unroll
    for (int ni = 0; ni < 4; ++ni) {
      int c = ni * 16 + l16;
      if (c < NCLS) se += expf(v[ni] - mx);
    }
    se += __shfl_xor(se, 1);
    se += __shfl_xor(se, 2);
    se += __shfl_xor(se, 4);
    se += __shfl_xor(se, 8);
    float lse = mx + logf(se);
#pragma unroll
    for (int ni = 0; ni < 4; ++ni) {
      int c = ni * 16 + l16;
      if (c < NCLS) out[(size_t)t * NCLS + c] = v[ni] - lse;
    }
  }
}

// ---------- launch ----------
extern "C" void kernel_launch(void* const* d_in, const int* in_sizes, int n_in,
                              void* d_out, int out_size, void* d_ws, size_t ws_size,
                              hipStream_t stream) {
  const float* x_nb  = (const float*)d_in[0];
  const float* ppr   = (const float*)d_in[1];
  const float* pca_w = (const float*)d_in[2];
  const float* pca_b = (const float*)d_in[3];
  const float* mlp_w = (const float*)d_in[4];
  const float* mlp_b = (const float*)d_in[5];
  const int* row_idx = (const int*)d_in[6];
  const int* col_idx = (const int*)d_in[7];
  float* out = (float*)d_out;

  char* ws = (char*)d_ws;
  const size_t OFF_BT   = 0;                                  // 512 KB
  const size_t OFF_BT2  = 512 * 1024;                         // 64 KB
  const size_t OFF_PPRN = 640 * 1024;                         // E*4 = 512 KB
  const size_t OFF_OFFS = 1152 * 1024;                        // (T+1)*4
  const size_t OFF_XN   = 1280 * 1024;                        // NB*512*2 = 102.4 MB
  const size_t OFF_UB   = OFF_XN + (size_t)NB_N * 512 * 2;    // T*512*2 = 16.8 MB
  u16*   Bt   = (u16*)(ws + OFF_BT);
  u16*   Bt2  = (u16*)(ws + OFF_BT2);
  float* pprn = (float*)(ws + OFF_PPRN);
  int*   offs = (int*)(ws + OFF_OFFS);
  u16*   xn   = (u16*)(ws + OFF_XN);
  u16*   ub   = (u16*)(ws + OFF_UB);

  conv_bt<<<1024, 256, 0, stream>>>(pca_w, Bt);
  conv_bt2<<<128, 256, 0, stream>>>(mlp_w, Bt2);
  build_offs<<<512, 256, 0, stream>>>(row_idx, offs);
  ppr_sm<<<64, 256, 0, stream>>>(ppr, offs, pprn);

  // 98 groups of 32 blocks: group g covers m-tiles 8g..8g+7 x all 4 n-tiles
  gemm_pca<<<98 * 32, 256, 0, stream>>>(x_nb, Bt, pca_b, xn);

  fused_all<<<T_N / 2, 128, 0, stream>>>(xn, col_idx, offs, pprn, ub);

  mlp_gemm<<<256, 256, 0, stream>>>(ub, Bt2, mlp_b, out);
}

// Round 11
// 444.243 us; speedup vs baseline: 1.0426x; 1.0134x over previous
//
#include <hip/hip_runtime.h>
#include <cstdint>
#include <cstddef>

// Problem constants (fixed by reference file)
#define NB_N 100000
#define E_N  131072
#define T_N  16384
#define D_N  512
#define NCLS 40
#define NTILES 782          // ceil(100000/128); 782*128 = 100096
#define CAPR 12             // legacy-path register z-cache edges/target

typedef unsigned short u16;
typedef unsigned int   u32;
typedef __attribute__((ext_vector_type(8))) short  short8;   // 8 bf16 (4 VGPRs)
typedef __attribute__((ext_vector_type(4))) float  floatx4;  // MFMA accumulator

// ---------- bf16 helpers (manual, RNE) ----------
__device__ __forceinline__ u16 f2bf(float f) {
  u32 u = __float_as_uint(f);
  return (u16)((u + 0x7fffu + ((u >> 16) & 1u)) >> 16);
}
__device__ __forceinline__ void unpack8(uint4 z, float* f) {
  f[0] = __uint_as_float(z.x << 16);
  f[1] = __uint_as_float(z.x & 0xffff0000u);
  f[2] = __uint_as_float(z.y << 16);
  f[3] = __uint_as_float(z.y & 0xffff0000u);
  f[4] = __uint_as_float(z.z << 16);
  f[5] = __uint_as_float(z.z & 0xffff0000u);
  f[6] = __uint_as_float(z.w << 16);
  f[7] = __uint_as_float(z.w & 0xffff0000u);
}
__device__ __forceinline__ void gload_lds16(const void* g, void* s) {
  __builtin_amdgcn_global_load_lds(
      (const __attribute__((address_space(1))) unsigned int*)g,
      (__attribute__((address_space(3))) unsigned int*)s, 16, 0, 0);
}
// packed f32x2 -> bf16x2 (RNE), hw instruction; bit-identical to f2bf on finite vals
__device__ __forceinline__ u32 cvtpk_bf16(float lo, float hi) {
  u32 r;
  asm("v_cvt_pk_bf16_f32 %0, %1, %2" : "=v"(r) : "v"(lo), "v"(hi));
  return r;
}

// ---------- kernel P: fused prep (3 independent roles, grid-partitioned).
//            blocks 0..63:   LDS-tiled transpose pca_w (512,512) f32 -> Bt bf16
//                            (coalesced read + coalesced write; +1-pad tile)
//            blocks 64..191: conv mlp_w (512,40) -> Bt2 (64,512) bf16, zero-pad
//            blocks 192..703: CSR offsets from sorted row_idx ----------
__global__ void prep(const float* __restrict__ w, const float* __restrict__ w2,
                     const int* __restrict__ rowi,
                     u16* __restrict__ Bt, u16* __restrict__ Bt2,
                     int* __restrict__ offs) {
  const int b = blockIdx.x, tid = threadIdx.x;
  if (b < 64) {
    __shared__ float T[64][65];           // +1 pad: conflict-free transposed reads
    const int tr = b >> 3, tc = b & 7;    // k-tile, n-tile (64x64)
    const int c0 = tid & 63;              // n-local on read, k-local on write
    const int r0 = tid >> 6;              // 0..3
#pragma unroll
    for (int i = 0; i < 16; ++i) {
      int kl = r0 * 16 + i;
      T[kl][c0] = w[(size_t)(tr * 64 + kl) * 512 + tc * 64 + c0];
    }
    __syncthreads();
#pragma unroll
    for (int i = 0; i < 16; ++i) {
      int nl = r0 + i * 4;
      Bt[(size_t)(tc * 64 + nl) * 512 + tr * 64 + c0] = f2bf(T[c0][nl]);
    }
  } else if (b < 192) {
    int i = (b - 64) * 256 + tid;         // 64*512 elements, i = n*512+k
    int n = i >> 9, k = i & 511;
    Bt2[i] = (n < NCLS) ? f2bf(w2[k * NCLS + n]) : (u16)0;
  } else {
    int e = (b - 192) * 256 + tid;
    if (e >= E_N) return;
    int r  = rowi[e];
    int rp = (e == 0) ? -1 : rowi[e - 1];
    for (int t = rp + 1; t <= r; ++t) offs[t] = e;
    if (e == E_N - 1)
      for (int t = r + 1; t <= T_N; ++t) offs[t] = E_N;
  }
}

// ---------- kernel 3: bf16 MFMA GEMM x = relu(x_nb @ pca_w + b), per-capsule l2norm,
//            writes xn bf16.
//            R12 config (PROVEN 130.5us, R8/R10): 128x128, 256 thr, BK=64,
//            3 blocks/CU, reg-staged A (single-buf) + dbuf DMA B, counted-vmcnt
//            2-barrier schedule with B issued 2 steps ahead. ----------
__global__ __launch_bounds__(256, 3) void gemm_pca(
    const float* __restrict__ A,    // x_nb (NB,512) f32
    const u16*   __restrict__ Bt,   // (512,512) bf16, n-major (pre-transposed)
    const float* __restrict__ bias, // (512,)
    u16*         __restrict__ xn) { // (NB,512) bf16, normalized
  __shared__ u16 SMEM[24576];       // 48 KB: As 128x64 (16KB) | Bs dbuf 2x 128x64 (32KB)
  u16* As = SMEM;
  u16* Bs = SMEM + 8192;            // buffer b at Bs + b*8192
  const int tid  = threadIdx.x;
  const int wid  = tid >> 6, lane = tid & 63;
  const int quad = lane >> 4, l16 = lane & 15;
  // XCD-grouped decode: b = 32g + 8n + mlow -> mt = 8g+mlow, n in {0..3}.
  const int b  = blockIdx.x;
  const int mt = (b & 7) | ((b >> 5) << 3);
  if (mt >= NTILES) return;
  const int m0 = mt * 128;
  const int n0 = ((b >> 3) & 3) * 128;
  const int wm = (wid >> 1) * 64;
  const int wn = (wid & 1) * 64;
  const int sw = l16 & 7;           // per-lane chunk swizzle for frag reads

  floatx4 acc[4][4];
#pragma unroll
  for (int i = 0; i < 4; ++i)
#pragma unroll
    for (int j = 0; j < 4; ++j) acc[i][j] = (floatx4){0.f, 0.f, 0.f, 0.f};

  float4 pa0[4], pa1[4];            // in-flight A regs: 4 units x 2 float4 (8 loads)

  auto issueA = [&](int k0) {
#pragma unroll
    for (int j = 0; j < 4; ++j) {
      int ci = j * 256 + tid;                 // 1024 units: row=ci>>3, kc=ci&7
      int row = ci >> 3, kc = ci & 7;
      int gm = m0 + row;
      if (gm > NB_N - 1) gm = NB_N - 1;       // clamp: exact vmcnt, rows never stored
      const float* src = A + (size_t)gm * 512 + k0 + kc * 8;
      pa0[j] = *(const float4*)(src);
      pa1[j] = *(const float4*)(src + 4);
    }
  };
  auto writeA = [&]() {
#pragma unroll
    for (int j = 0; j < 4; ++j) {
      int ci = j * 256 + tid;
      int row = ci >> 3, kc = ci & 7;
      uint4 pk;
      pk.x = cvtpk_bf16(pa0[j].x, pa0[j].y);
      pk.y = cvtpk_bf16(pa0[j].z, pa0[j].w);
      pk.z = cvtpk_bf16(pa1[j].x, pa1[j].y);
      pk.w = cvtpk_bf16(pa1[j].z, pa1[j].w);
      int dc = kc ^ (row & 7);                // dest-side swizzle
      *(uint4*)(&As[(size_t)(row * 8 + dc) * 8]) = pk;
    }
  };
  auto issueB = [&](int k0, u16* dstB) {
#pragma unroll
    for (int j = 0; j < 4; ++j) {
      int ci  = j * 256 + wid * 64 + lane;    // 1024 chunks
      int row = ci >> 3;
      int kcs = (lane & 7) ^ ((lane >> 3) & 7);
      gload_lds16(Bt + (size_t)(n0 + row) * 512 + k0 + kcs * 8,
                  &dstB[(size_t)(j * 256 + wid * 64) * 8]);
    }
  };

  // ---- prologue: A0, B0, B1 staged; A1 in flight ----
  issueA(0);                          // A0: 8 loads
  issueB(0, Bs);                      // B0 -> slot 0 (4 DMA)
  issueB(64, Bs + 8192);              // B1 -> slot 1 (4 DMA)
  writeA();                           // implicit vmcnt(8): A0 done; B0,B1 in flight
  issueA(64);                         // A1: 8 loads
  asm volatile("s_waitcnt vmcnt(12) lgkmcnt(0)" ::: "memory");  // drain B0; keep B1+A1
  __builtin_amdgcn_s_barrier();
  __builtin_amdgcn_sched_barrier(0);

  // ---- main loop: 8 k-steps, 2 barriers/step; B issued 2 steps ahead ----
#pragma unroll
  for (int s = 0; s < 8; ++s) {
    const int cs = s & 1;
    const u16* Bsc = Bs + cs * 8192;
    // compute step s (reads As + Bsc)
#pragma unroll
    for (int kk = 0; kk < 64; kk += 32) {
      short8 af[4], bf[4];
#pragma unroll
      for (int mi = 0; mi < 4; ++mi) {
        int c = (kk >> 3) + quad;
        af[mi] = *(const short8*)(&As[(wm + mi * 16 + l16) * 64 + ((c ^ sw) << 3)]);
      }
#pragma unroll
      for (int ni = 0; ni < 4; ++ni) {
        int c = (kk >> 3) + quad;
        bf[ni] = *(const short8*)(&Bsc[(wn + ni * 16 + l16) * 64 + ((c ^ sw) << 3)]);
      }
#pragma unroll
      for (int mi = 0; mi < 4; ++mi)
#pragma unroll
        for (int ni = 0; ni < 4; ++ni)
          acc[mi][ni] = __builtin_amdgcn_mfma_f32_16x16x32_bf16(af[mi], bf[ni],
                                                                acc[mi][ni], 0, 0, 0);
    }
    // barrier 1: all waves done READING As + Bs[cs] (slot cs now free)
    __builtin_amdgcn_s_barrier();
    __builtin_amdgcn_sched_barrier(0);
    if (s + 1 < 8) {
      if (s + 2 < 8) issueB((s + 2) * 64, Bs + cs * 8192);  // slot (s+2)&1 == cs
      writeA();                       // implicit wait: A(s+1) done -> B(s+1) (older) done
      if (s + 2 < 8) {
        issueA((s + 2) * 64);         // refill A regs (8 loads)
        asm volatile("s_waitcnt vmcnt(12) lgkmcnt(0)" ::: "memory");  // keep B(s+2)+A(s+2)
      } else {
        asm volatile("s_waitcnt vmcnt(0) lgkmcnt(0)" ::: "memory");   // tail: drain all
      }
      __builtin_amdgcn_s_barrier();   // barrier 2: As written + B(s+1) resident
      __builtin_amdgcn_sched_barrier(0);
    }
  }
  __syncthreads();                    // all compute done before Os overwrites SMEM

  // epilogue: +bias, relu, per-capsule (64-col) l2norm -> LDS tile -> full-line stores
  u16* Os = SMEM;                     // 128x128 u16 = 32 KB (As/Bs dead)
#pragma unroll
  for (int mi = 0; mi < 4; ++mi) {
#pragma unroll
    for (int r = 0; r < 4; ++r) {
      int lrow = wm + mi * 16 + quad * 4 + r;
      float v[4];
      float ss = 0.f;
#pragma unroll
      for (int ni = 0; ni < 4; ++ni) {
        int n  = n0 + wn + ni * 16 + l16;
        float x = acc[mi][ni][r] + bias[n];
        x = fmaxf(x, 0.f);
        v[ni] = x;
        ss += x * x;
      }
      ss += __shfl_xor(ss, 1);
      ss += __shfl_xor(ss, 2);
      ss += __shfl_xor(ss, 4);
      ss += __shfl_xor(ss, 8);
      float sc = 1.f / fmaxf(sqrtf(ss), 1e-12f);
#pragma unroll
      for (int ni = 0; ni < 4; ++ni)
        Os[lrow * 128 + wn + ni * 16 + l16] = f2bf(v[ni] * sc);
    }
  }
  __syncthreads();
#pragma unroll
  for (int c8 = 0; c8 < 8; ++c8) {    // 2048 16B-chunks, 8 per thread
    int idx = c8 * 256 + tid;
    int row = idx >> 4, chk = idx & 15;
    int gm = m0 + row;
    if (gm < NB_N) {
      uint4 val = *(const uint4*)(&Os[row * 128 + chk * 8]);
      *(uint4*)(xn + (size_t)gm * 512 + n0 + chk * 8) = val;
    }
  }
}

// ---------- fast-path helpers for kernel 4 ----------
// matvec in coefficient space: e_i = sum_j G[i][j] * w[j], rows i0 / i0+8 per lane.
// w[c][j] lives at lane (c*8 | (j&7)), register w0 (j<8) / w1 (j>=8).
__device__ __forceinline__ void matvec16(const float (&g0)[16], const float (&g1)[16],
                                         float w0, float w1, int base,
                                         float& e0, float& e1) {
  e0 = 0.f; e1 = 0.f;
#pragma unroll
  for (int j = 0; j < 8; ++j) {
    float wj = __shfl(w0, base | j);
    e0 += g0[j] * wj;
    e1 += g1[j] * wj;
  }
#pragma unroll
  for (int j = 0; j < 8; ++j) {
    float wj = __shfl(w1, base | j);
    e0 += g0[8 + j] * wj;
    e1 += g1[8 + j] * wj;
  }
}

// segment softmax over edges of one capsule: values d0 (edge i0), d1 (edge i0+8),
// reduction across the 8 lanes of the capsule group (xor 1,2,4). Invalid -> 0.
__device__ __forceinline__ void segsm2(float& d0, float& d1, bool v0, bool v1) {
  float m = fmaxf(v0 ? d0 : -INFINITY, v1 ? d1 : -INFINITY);
  m = fmaxf(m, __shfl_xor(m, 1));
  m = fmaxf(m, __shfl_xor(m, 2));
  m = fmaxf(m, __shfl_xor(m, 4));
  float e0 = v0 ? expf(d0 - m) : 0.f;
  float e1 = v1 ? expf(d1 - m) : 0.f;
  float s = e0 + e1;
  s += __shfl_xor(s, 1);
  s += __shfl_xor(s, 2);
  s += __shfl_xor(s, 4);
  float inv = 1.f / s;
  d0 = e0 * inv;
  d1 = e1 * inv;
}

// ---------- kernel 4: ALL routing (init + 3 rounds), one target per wave.
//            R15: ppr segment-softmax inlined (wave-wide shfl_xor reduce over
//            lanes [0,deg) of the raw ppr) -> ppr_sm kernel + pprn buffer gone.
//            Zlds stash dropped (R14 neutral: gather savings canceled by the
//            16->6 waves/CU occupancy loss) -> back to 16 waves/CU.
//            FAST PATH (deg<=16): Gram via MFMA, routing in coefficient space.
//            LEGACY PATH (deg>16): edge loop. ----------
__global__ __launch_bounds__(128, 4) void fused_all(
    const u16* __restrict__ xn, const int* __restrict__ coli,
    const int* __restrict__ offs, const float* __restrict__ ppr,
    u16* __restrict__ ub) {
  // per-wave Gram staging: stored[c][a][b] = G_c[b][a], 260-float capsule stride
  __shared__ __align__(16) float Glds[2][8 * 260];
  const int lane = threadIdx.x & 63;
  const int wv = threadIdx.x >> 6;
  const int t = blockIdx.x * 2 + wv;
  const int s = offs[t], en = offs[t + 1];
  int deg = en - s;
  if (deg > 64) deg = 64;           // Poisson(8): max over 16k targets ~27

  int   mycol = (lane < deg) ? coli[s + lane] : 0;
  float praw  = (lane < deg) ? ppr[s + lane] : 0.f;

  // in-wave segment softmax of raw ppr over lanes [0,deg)  (replaces ppr_sm)
  float myppr;
  {
    float v = (lane < deg) ? praw : -INFINITY;
    float m = v;
    m = fmaxf(m, __shfl_xor(m, 1));
    m = fmaxf(m, __shfl_xor(m, 2));
    m = fmaxf(m, __shfl_xor(m, 4));
    m = fmaxf(m, __shfl_xor(m, 8));
    m = fmaxf(m, __shfl_xor(m, 16));
    m = fmaxf(m, __shfl_xor(m, 32));
    float e = (lane < deg) ? expf(praw - m) : 0.f;
    float ss = e;
    ss += __shfl_xor(ss, 1);
    ss += __shfl_xor(ss, 2);
    ss += __shfl_xor(ss, 4);
    ss += __shfl_xor(ss, 8);
    ss += __shfl_xor(ss, 16);
    ss += __shfl_xor(ss, 32);
    myppr = e / ss;                 // deg=0 -> NaN, but uf-loops skip -> unused
  }

  float uf[8] = {0.f, 0.f, 0.f, 0.f, 0.f, 0.f, 0.f, 0.f};

  if (deg <= 16) {
    // ================= fast path =================
    float* G = Glds[wv];
    // 1) gather z fragments (lane: edge=lane&15, k-chunk=lane>>4) and build Grams
    const int esrc = lane & 15, kq = lane >> 4;
    int ce = __shfl(mycol, esrc);                 // edges >= deg read row 0 (masked later)
    const u16* zb = xn + (size_t)ce * 512 + kq * 8;
    floatx4 gram[8];
#pragma unroll
    for (int c = 0; c < 8; ++c) {
      short8 f0 = *(const short8*)(zb + c * 64);
      short8 f1 = *(const short8*)(zb + c * 64 + 32);
      floatx4 gg = (floatx4){0.f, 0.f, 0.f, 0.f};
      gg = __builtin_amdgcn_mfma_f32_16x16x32_bf16(f0, f0, gg, 0, 0, 0);
      gg = __builtin_amdgcn_mfma_f32_16x16x32_bf16(f1, f1, gg, 0, 0, 0);
      gram[c] = gg;
    }
    // 2) D layout: lane holds G[i=kq*4+r][j=esrc]; store as [c][esrc][kq*4+r]
#pragma unroll
    for (int c = 0; c < 8; ++c)
      *(float4*)&G[c * 260 + esrc * 16 + kq * 4] = *(float4*)&gram[c];
    // 3) lane (c=lane>>3, i0=lane&7) loads rows i0 and i0+8 of its capsule's Gram
    const int cc = lane >> 3, i0 = lane & 7;
    const int base = lane & 56;                   // == cc*8, bpermute broadcast base
    float g0[16], g1[16];
    {
      const float* r0 = &G[cc * 260 + i0 * 16];
      const float* r1 = &G[cc * 260 + (i0 + 8) * 16];
#pragma unroll
      for (int ch = 0; ch < 4; ++ch) {
        float4 a = *(const float4*)(r0 + ch * 4);
        float4 b = *(const float4*)(r1 + ch * 4);
        g0[ch * 4 + 0] = a.x; g0[ch * 4 + 1] = a.y;
        g0[ch * 4 + 2] = a.z; g0[ch * 4 + 3] = a.w;
        g1[ch * 4 + 0] = b.x; g1[ch * 4 + 1] = b.y;
        g1[ch * 4 + 2] = b.z; g1[ch * 4 + 3] = b.w;
      }
    }
    const bool v0 = i0 < deg, v1 = (i0 + 8) < deg;
    float pr0 = __shfl(myppr, i0);                // ppr[i0], 0 if invalid
    float pr1 = __shfl(myppr, i0 + 8);

    // init logits: d = G . ppr  (== <u0, z_i>, u0 = sum ppr_j z_j, unnormalized)
    float d0, d1;
    matvec16(g0, g1, pr0, pr1, base, d0, d1);

    float w0 = 0.f, w1 = 0.f;
#pragma unroll
    for (int it = 0; it < 3; ++it) {
      segsm2(d0, d1, v0, v1);                     // first segment softmax
      d0 = 0.5f * d0 + 0.5f * pr0;                // blend with pprn (invalid: 0+0)
      d1 = 0.5f * d1 + 0.5f * pr1;
      segsm2(d0, d1, v0, v1);                     // second segment softmax -> P
      w0 = d0; w1 = d1;                           // coefficients (invalid == 0)
      if (it < 2) {
        // e = G.P serves both the l2norm (||u||^2 = P^T G P) and next logits
        float e0, e1;
        matvec16(g0, g1, w0, w1, base, e0, e1);
        float nv = w0 * e0 + w1 * e1;
        nv += __shfl_xor(nv, 1);
        nv += __shfl_xor(nv, 2);
        nv += __shfl_xor(nv, 4);
        float invn = 1.f / fmaxf(sqrtf(nv), 1e-12f);
        d0 = e0 * invn;
        d1 = e1 * invn;
      }
    }

    // final reconstruction: u = sum_j P2_j z_j (lane holds dims of capsule lane>>3)
#pragma unroll
    for (int j = 0; j < 16; ++j) {
      if (j < deg) {                              // wave-uniform branch
        float wj = __shfl((j < 8) ? w0 : w1, base | (j & 7));
        int cj = __shfl(mycol, j);
        uint4 zz = *(const uint4*)(xn + (size_t)cj * 512 + lane * 8);
        float zf[8];
        unpack8(zz, zf);
#pragma unroll
        for (int q = 0; q < 8; ++q) uf[q] += wj * zf[q];
      }
    }
  } else {
    // ================= legacy path (deg > 16, ~0.4% of targets) =================
    const int cap = lane >> 3;
    const int slot = lane >> 3;

    uint4 zreg[CAPR];
#pragma unroll
    for (int j = 0; j < CAPR; ++j) {
      if (j < deg) {
        int c = __shfl(mycol, j);
        zreg[j] = *(const uint4*)(xn + (size_t)c * 512 + lane * 8);
      }
    }

    // init: u0 = sum_e pprn_e * z_e
#pragma unroll
    for (int j = 0; j < CAPR; ++j) {
      if (j < deg) {
        float w = __shfl(myppr, j);
        float zf[8];
        unpack8(zreg[j], zf);
#pragma unroll
        for (int q = 0; q < 8; ++q) uf[q] += w * zf[q];
      }
    }
    for (int j = CAPR; j < deg; ++j) {
      float w = __shfl(myppr, j);
      int c = __shfl(mycol, j);
      uint4 zz = *(const uint4*)(xn + (size_t)c * 512 + lane * 8);
      float zf[8];
      unpack8(zz, zf);
#pragma unroll
      for (int q = 0; q < 8; ++q) uf[q] += w * zf[q];
    }

    float Preg[8];

    for (int it = 0; it < 3; ++it) {
      // ---- phase 1: capsule logits ----
#pragma unroll
      for (int j = 0; j < CAPR; ++j) {
        if (j < deg) {
          float zf[8];
          unpack8(zreg[j], zf);
          float d = uf[0]*zf[0] + uf[1]*zf[1] + uf[2]*zf[2] + uf[3]*zf[3] +
                    uf[4]*zf[4] + uf[5]*zf[5] + uf[6]*zf[6] + uf[7]*zf[7];
          d += __shfl_xor(d, 1);
          d += __shfl_xor(d, 2);
          d += __shfl_xor(d, 4);
          float dc = __shfl(d, (lane & 7) << 3);
          if (slot == (j & 7)) Preg[j >> 3] = dc;
        }
      }
      for (int j = CAPR; j < deg; ++j) {
        int c = __shfl(mycol, j);
        uint4 zz = *(const uint4*)(xn + (size_t)c * 512 + lane * 8);
        float zf[8];
        unpack8(zz, zf);
        float d = uf[0]*zf[0] + uf[1]*zf[1] + uf[2]*zf[2] + uf[3]*zf[3] +
                  uf[4]*zf[4] + uf[5]*zf[5] + uf[6]*zf[6] + uf[7]*zf[7];
        d += __shfl_xor(d, 1);
        d += __shfl_xor(d, 2);
        d += __shfl_xor(d, 4);
        float dc = __shfl(d, (lane & 7) << 3);
        if (slot == (j & 7)) {
          int hi = j >> 3;
          if      (hi == 1) Preg[1] = dc;
          else if (hi == 2) Preg[2] = dc;
          else if (hi == 3) Preg[3] = dc;
          else if (hi == 4) Preg[4] = dc;
          else if (hi == 5) Preg[5] = dc;
          else if (hi == 6) Preg[6] = dc;
          else if (hi == 7) Preg[7] = dc;
        }
      }

      // ---- phase 2: segsm -> blend -> segsm ----
      {
        float m1 = -INFINITY;
#pragma unroll
        for (int i = 0; i < 8; ++i)
          m1 = (slot + 8*i < deg) ? fmaxf(m1, Preg[i]) : m1;
        m1 = fmaxf(m1, __shfl_xor(m1, 8));
        m1 = fmaxf(m1, __shfl_xor(m1, 16));
        m1 = fmaxf(m1, __shfl_xor(m1, 32));
        float s1 = 0.f;
#pragma unroll
        for (int i = 0; i < 8; ++i)
          s1 += (slot + 8*i < deg) ? expf(Preg[i] - m1) : 0.f;
        s1 += __shfl_xor(s1, 8);
        s1 += __shfl_xor(s1, 16);
        s1 += __shfl_xor(s1, 32);
        float inv1 = 1.f / s1;
        float m2 = -INFINITY;
#pragma unroll
        for (int i = 0; i < 8; ++i) {
          int j = slot + 8*i;
          if (j < deg) {
            float pj = __shfl(myppr, j);
            float v = 0.5f * expf(Preg[i] - m1) * inv1 + 0.5f * pj;
            Preg[i] = v;
            m2 = fmaxf(m2, v);
          }
        }
        m2 = fmaxf(m2, __shfl_xor(m2, 8));
        m2 = fmaxf(m2, __shfl_xor(m2, 16));
        m2 = fmaxf(m2, __shfl_xor(m2, 32));
        float s2 = 0.f;
#pragma unroll
        for (int i = 0; i < 8; ++i)
          s2 += (slot + 8*i < deg) ? expf(Preg[i] - m2) : 0.f;
        s2 += __shfl_xor(s2, 8);
        s2 += __shfl_xor(s2, 16);
        s2 += __shfl_xor(s2, 32);
        float inv2 = 1.f / s2;
#pragma unroll
        for (int i = 0; i < 8; ++i)
          if (slot + 8*i < deg) Preg[i] = expf(Preg[i] - m2) * inv2;
      }

      // ---- phase 3: u_new ----
      float acc[8] = {0.f, 0.f, 0.f, 0.f, 0.f, 0.f, 0.f, 0.f};
#pragma unroll
      for (int j = 0; j < CAPR; ++j) {
        if (j < deg) {
          float w = __shfl(Preg[j >> 3], ((j & 7) << 3) | cap);
          float zf[8];
          unpack8(zreg[j], zf);
#pragma unroll
          for (int q = 0; q < 8; ++q) acc[q] += w * zf[q];
        }
      }
      for (int j = CAPR; j < deg; ++j) {
        int hi = j >> 3;
        float pr = Preg[1];
        if      (hi == 2) pr = Preg[2];
        else if (hi == 3) pr = Preg[3];
        else if (hi == 4) pr = Preg[4];
        else if (hi == 5) pr = Preg[5];
        else if (hi == 6) pr = Preg[6];
        else if (hi == 7) pr = Preg[7];
        float w = __shfl(pr, ((j & 7) << 3) | cap);
        int c = __shfl(mycol, j);
        uint4 zz = *(const uint4*)(xn + (size_t)c * 512 + lane * 8);
        float zf[8];
        unpack8(zz, zf);
#pragma unroll
        for (int q = 0; q < 8; ++q) acc[q] += w * zf[q];
      }
      if (it < 2) {
        float ss = 0.f;
#pragma unroll
        for (int q = 0; q < 8; ++q) ss += acc[q] * acc[q];
        ss += __shfl_xor(ss, 1);
        ss += __shfl_xor(ss, 2);
        ss += __shfl_xor(ss, 4);
        float sc = 1.f / fmaxf(sqrtf(ss), 1e-12f);
#pragma unroll
        for (int q = 0; q < 8; ++q) acc[q] *= sc;
      }
#pragma unroll
      for (int q = 0; q < 8; ++q) uf[q] = acc[q];
    }
  }

  // output: ub = bf16(relu(u)) for the MLP GEMM
  uint4 pk;
  pk.x = (u32)f2bf(fmaxf(uf[0], 0.f)) | ((u32)f2bf(fmaxf(uf[1], 0.f)) << 16);
  pk.y = (u32)f2bf(fmaxf(uf[2], 0.f)) | ((u32)f2bf(fmaxf(uf[3], 0.f)) << 16);
  pk.z = (u32)f2bf(fmaxf(uf[4], 0.f)) | ((u32)f2bf(fmaxf(uf[5], 0.f)) << 16);
  pk.w = (u32)f2bf(fmaxf(uf[6], 0.f)) | ((u32)f2bf(fmaxf(uf[7], 0.f)) << 16);
  *(uint4*)(ub + (size_t)t * 512 + lane * 8) = pk;
}

// ---------- kernel 5: logits = ub @ Bt2^T + mb; fused log_softmax epilogue. ----------
__global__ __launch_bounds__(256) void mlp_gemm(
    const u16* __restrict__ ub, const u16* __restrict__ Bt2,
    const float* __restrict__ mb, float* __restrict__ out) {
  const int wid = threadIdx.x >> 6, lane = threadIdx.x & 63;
  const int quad = lane >> 4, l16 = lane & 15;
  const int m0 = blockIdx.x * 64 + wid * 16;

  floatx4 acc[4];
#pragma unroll
  for (int ni = 0; ni < 4; ++ni) acc[ni] = (floatx4){0.f, 0.f, 0.f, 0.f};

#pragma unroll 4
  for (int kk = 0; kk < 512; kk += 32) {
    short8 af = *(const short8*)(ub + (size_t)(m0 + l16) * 512 + kk + quad * 8);
#pragma unroll
    for (int ni = 0; ni < 4; ++ni) {
      short8 bf = *(const short8*)(Bt2 + (size_t)(ni * 16 + l16) * 512 + kk + quad * 8);
      acc[ni] = __builtin_amdgcn_mfma_f32_16x16x32_bf16(af, bf, acc[ni], 0, 0, 0);
    }
  }

#pragma unroll
  for (int r = 0; r < 4; ++r) {
    int t = m0 + quad * 4 + r;
    float v[4];
    float mx = -INFINITY;
#pragma unroll
    for (int ni = 0; ni < 4; ++ni) {
      int c = ni * 16 + l16;
      float lg = (c < NCLS) ? (acc[ni][r] + mb[c]) : -INFINITY;
      v[ni] = lg;
      mx = fmaxf(mx, lg);
    }
    mx = fmaxf(mx, __shfl_xor(mx, 1));
    mx = fmaxf(mx, __shfl_xor(mx, 2));
    mx = fmaxf(mx, __shfl_xor(mx, 4));
    mx = fmaxf(mx, __shfl_xor(mx, 8));
    float se = 0.f;
#pragma unroll
    for (int ni = 0; ni < 4; ++ni) {
      int c = ni * 16 + l16;
      if (c < NCLS) se += expf(v[ni] - mx);
    }
    se += __shfl_xor(se, 1);
    se += __shfl_xor(se, 2);
    se += __shfl_xor(se, 4);
    se += __shfl_xor(se, 8);
    float lse = mx + logf(se);
#pragma unroll
    for (int ni = 0; ni < 4; ++ni) {
      int c = ni * 16 + l16;
      if (c < NCLS) out[(size_t)t * NCLS + c] = v[ni] - lse;
    }
  }
}

// ---------- launch ----------
extern "C" void kernel_launch(void* const* d_in, const int* in_sizes, int n_in,
                              void* d_out, int out_size, void* d_ws, size_t ws_size,
                              hipStream_t stream) {
  const float* x_nb  = (const float*)d_in[0];
  const float* ppr   = (const float*)d_in[1];
  const float* pca_w = (const float*)d_in[2];
  const float* pca_b = (const float*)d_in[3];
  const float* mlp_w = (const float*)d_in[4];
  const float* mlp_b = (const float*)d_in[5];
  const int* row_idx = (const int*)d_in[6];
  const int* col_idx = (const int*)d_in[7];
  float* out = (float*)d_out;

  char* ws = (char*)d_ws;
  const size_t OFF_BT   = 0;                                  // 512 KB
  const size_t OFF_BT2  = 512 * 1024;                         // 64 KB
  const size_t OFF_OFFS = 640 * 1024;                         // (T+1)*4
  const size_t OFF_XN   = 768 * 1024;                         // NB*512*2 = 102.4 MB
  const size_t OFF_UB   = OFF_XN + (size_t)NB_N * 512 * 2;    // T*512*2 = 16.8 MB
  u16*   Bt   = (u16*)(ws + OFF_BT);
  u16*   Bt2  = (u16*)(ws + OFF_BT2);
  int*   offs = (int*)(ws + OFF_OFFS);
  u16*   xn   = (u16*)(ws + OFF_XN);
  u16*   ub   = (u16*)(ws + OFF_UB);

  // one prep kernel: Bt transpose (64 blocks) | Bt2 (128) | offs (512)
  prep<<<704, 256, 0, stream>>>(pca_w, mlp_w, row_idx, Bt, Bt2, offs);

  // 98 groups of 32 blocks: group g covers m-tiles 8g..8g+7 x all 4 n-tiles
  gemm_pca<<<98 * 32, 256, 0, stream>>>(x_nb, Bt, pca_b, xn);

  fused_all<<<T_N / 2, 128, 0, stream>>>(xn, col_idx, offs, ppr, ub);

  mlp_gemm<<<256, 256, 0, stream>>>(ub, Bt2, mlp_b, out);
}